// Round 16
// baseline (407.827 us; speedup 1.0000x reference)
//
#include <hip/hip_runtime.h>
#include <hip/hip_fp16.h>
#include <math.h>

#define Bv 4096
#define Sv 64
#define Ev 128
#define Hv 256
#define Cv 18
#define Mrows 8      // sequences per block (M=8 of the MFMA's 16 rows used)
#define WRDS 3072    // words per step buffer: AH kb0..11 (emb kb0-3, h kb4-11)

typedef _Float16 hfrag __attribute__((ext_vector_type(8)));
using f4v = __attribute__((ext_vector_type(4))) float;

#define LO_SCALE 2048.0f            // 2^11 on w1_lo (FC1 only)
#define LO_DESCALE (1.0f / 2048.0f)

// XOR swizzle: flips bits 2-4 by a hash of higher bits. Bits 0-1 preserved
// -> b128/uint2 contiguity kept; balances scattered writes across banks while
// reads remain the canonical conflict-free lane*16B pattern.
__device__ inline int SW(int o) {
    return o ^ ((((o >> 5) ^ (o >> 8)) & 7) << 2);
}

__device__ inline float fast_tanh(float x) {
    float e = __expf(x + x);
    return 1.0f - 2.0f * __builtin_amdgcn_rcpf(e + 1.0f);
}

__device__ inline unsigned pk_h2(float a, float b) {
    unsigned ua = __half_as_ushort(__float2half_rn(a));
    unsigned ub = __half_as_ushort(__float2half_rn(b));
    return ua | (ub << 16);
}

// ---- kernel A: build MFMA fragments: rnn W (f16 hi only), W1 (hi + lo*2^11) ----
__global__ void build_frags(const float* __restrict__ W_ih,
                            const float* __restrict__ W_hh,
                            const float* __restrict__ W1,
                            unsigned* __restrict__ wfh,
                            unsigned* __restrict__ wf1h, unsigned* __restrict__ wf1l) {
    int f = blockIdx.x * 256 + threadIdx.x;   // 0..20479
    bool isrnn = f < 12288;
    int g = isrnn ? f : f - 12288;
    int lane = g & 63, tile = (g >> 6) & 15, kb = g >> 10;
    int q = lane >> 4, col = lane & 15;
    int n = tile * 16 + col;
    unsigned hu[8], lu[8];
    #pragma unroll
    for (int j = 0; j < 8; ++j) {
        int k = kb * 32 + q * 8 + j;
        float x;
        if (isrnn) x = (k < Ev) ? W_ih[n * Ev + k] : W_hh[n * Hv + (k - Ev)];
        else       x = W1[n * Hv + k];
        __half h = __float2half_rn(x);
        hu[j] = __half_as_ushort(h);
        float l = (x - __half2float(h)) * LO_SCALE;
        lu[j] = __half_as_ushort(__float2half_rn(l));
    }
    unsigned* oh = (isrnn ? wfh : wf1h) + (size_t)g * 4;
    #pragma unroll
    for (int d = 0; d < 4; ++d) oh[d] = hu[2 * d] | (hu[2 * d + 1] << 16);
    if (!isrnn) {
        unsigned* ol = wf1l + (size_t)g * 4;
        #pragma unroll
        for (int d = 0; d < 4; ++d) ol[d] = lu[2 * d] | (lu[2 * d + 1] << 16);
    }
}

// ---- kernel B: fused recurrence + FC head; 8 waves x 2 N-tiles, W pinned ----
// 8 sequences/block, grid 512 -> 2 blocks/CU co-resident (4 waves/SIMD TLP).
__global__ __launch_bounds__(512, 4) void rnn_fused(
    const int* __restrict__ x_in, const int* __restrict__ x_len,
    const float* __restrict__ emb,
    const unsigned* __restrict__ wfh,
    const unsigned* __restrict__ wf1h, const unsigned* __restrict__ wf1l,
    const float* __restrict__ b_ih, const float* __restrict__ b_hh,
    const float* __restrict__ b1, const float* __restrict__ W2,
    const float* __restrict__ b2, float* __restrict__ out)
{
    __shared__ unsigned SH[2 * WRDS];   // 24 KB step buffers (f16 A fragments)
    __shared__ unsigned LF[2048];       // 8 KB last-h fragments
    float* yb = reinterpret_cast<float*>(SH);   // fc y buffer aliases SH after loop

    const int tid = threadIdx.x;
    const int lane = tid & 63, w = tid >> 6;     // wave 0..7
    const int q = lane >> 4, col = lane & 15;
    const int rb = blockIdx.x * Mrows;

    // resident W: tiles 2w, 2w+1 -> f16 hi all 12 kb (96 regs)
    hfrag wh[2][12];
    #pragma unroll
    for (int i = 0; i < 2; ++i) {
        const int ti = 2 * w + i;
        #pragma unroll
        for (int kb = 0; kb < 12; ++kb) {
            int fid = (kb * 16 + ti) * 64 + lane;
            wh[i][kb] = *reinterpret_cast<const hfrag*>(&wfh[(size_t)fid * 4]);
        }
    }
    #pragma unroll
    for (int i = 0; i < 2; ++i)
        #pragma unroll
        for (int kb = 0; kb < 12; ++kb) asm volatile("" : "+v"(wh[i][kb]));

    // bias folded into MFMA C-init
    f4v bcv[2];
    #pragma unroll
    for (int i = 0; i < 2; ++i)
        #pragma unroll
        for (int r = 0; r < 4; ++r) {
            int n = (2 * w + i) * 16 + 4 * q + r;
            bcv[i][r] = b_ih[n] + b_hh[n];
        }
    // lengths: valid for col 0..7; col 8..15 read the duplicate
    const int len_c = x_len[rb + (col & 7)];
    int tmax = len_c;
    #pragma unroll
    for (int m = 1; m < 16; m <<= 1) {
        int o = __shfl_xor(tmax, m, 64);
        tmax = tmax > o ? tmax : o;
    }

    // zero h region of buffer 0 (words 1024..3071; SW permutes within)
    for (int u = tid; u < 2048; u += 512) SH[1024 + u] = 0u;

    // emb staging: waves 0..3 stage rows 0..7 (em<8); waves 4..7 idle here
    const int em = tid >> 5;            // 0..15; valid row if <8
    const bool stager = em < 8;
    const int ek = (tid & 31) * 4;      // k 0..124
    const int eo = (ek >> 5) * 256 + ((((ek >> 3) & 3) * 16 + em) * 4) + (((ek >> 2) & 1) * 2);
    const int* xrow = x_in + (rb + em) * Sv;   // deref only if stager

    float4 ev_cur;
    if (stager) {
        float4 e0 = *(const float4*)&emb[(size_t)xrow[0] * Ev + ek];
        *reinterpret_cast<uint2*>(&SH[SW(eo)]) =
            make_uint2(pk_h2(e0.x, e0.y), pk_h2(e0.z, e0.w));
        ev_cur = *(const float4*)&emb[(size_t)xrow[1] * Ev + ek];
    }
    uint2 snap[2];
    snap[0] = snap[1] = make_uint2(0u, 0u);
    __syncthreads();

    #pragma unroll 1
    for (int t = 0; t < tmax; ++t) {
        const int rbuf = (t & 1) * WRDS;
        const int wbuf = ((t + 1) & 1) * WRDS;

        // prefetch emb row for t+2
        float4 ev_next;
        if (stager && t + 2 < Sv) {
            int tok = xrow[t + 2];
            ev_next = *(const float4*)&emb[(size_t)tok * Ev + ek];
        }

        // 4 accumulator chains: hi even/odd per tile, bias folded in even
        f4v aHe0 = bcv[0], aHe1 = bcv[1];
        f4v z = {0.f, 0.f, 0.f, 0.f};
        f4v aHo0 = z, aHo1 = z;

        #pragma unroll
        for (int kb = 0; kb < 12; ++kb) {
            hfrag ah = *reinterpret_cast<const hfrag*>(&SH[rbuf + SW(kb * 256 + lane * 4)]);
            if (kb & 1) {
                aHo0 = __builtin_amdgcn_mfma_f32_16x16x32_f16(wh[0][kb], ah, aHo0, 0, 0, 0);
                aHo1 = __builtin_amdgcn_mfma_f32_16x16x32_f16(wh[1][kb], ah, aHo1, 0, 0, 0);
            } else {
                aHe0 = __builtin_amdgcn_mfma_f32_16x16x32_f16(wh[0][kb], ah, aHe0, 0, 0, 0);
                aHe1 = __builtin_amdgcn_mfma_f32_16x16x32_f16(wh[1][kb], ah, aHe1, 0, 0, 0);
            }
        }

        // stage emb for t+1 early (overlaps MFMA tail)
        if (stager && t + 1 < Sv) {
            *reinterpret_cast<uint2*>(&SH[wbuf + SW(eo)]) =
                make_uint2(pk_h2(ev_cur.x, ev_cur.y), pk_h2(ev_cur.z, ev_cur.w));
        }

        // epilogue: lane holds h[m=col][n = ti*16 + 4q + r]; m>=8 rows are
        // don't-care (garbage stays confined to D rows 8..15, discarded).
        #pragma unroll
        for (int i = 0; i < 2; ++i) {
            f4v s = (i == 0) ? (aHe0 + aHo0) : (aHe1 + aHo1);
            const int ti = 2 * w + i;
            float hv[4];
            #pragma unroll
            for (int r = 0; r < 4; ++r)
                hv[r] = fast_tanh(s[r]);
            const int dl = ((ti & 1) * 2 + (q >> 1)) * 16 + col;
            const uint2 hu = make_uint2(pk_h2(hv[0], hv[1]), pk_h2(hv[2], hv[3]));
            const int oAH = (4 + (ti >> 1)) * 256 + dl * 4 + (q & 1) * 2;
            *reinterpret_cast<uint2*>(&SH[wbuf + SW(oAH)]) = hu;
            if (t == len_c - 1) snap[i] = hu;
        }
        ev_cur = ev_next;
        __syncthreads();
    }

    // ---- write last-h snapshots to LF once ----
    #pragma unroll
    for (int i = 0; i < 2; ++i) {
        const int ti = 2 * w + i;
        const int dl = ((ti & 1) * 2 + (q >> 1)) * 16 + col;
        const int oLH = (ti >> 1) * 256 + dl * 4 + (q & 1) * 2;
        *reinterpret_cast<uint2*>(&LF[SW(oLH)]) = snap[i];
    }
    __syncthreads();

    // ---- fused FC1 (MFMA, f16 hi+lo) on LF ----
    f4v fH0, fH1, fL0, fL1;
    {
        float4 bb0 = *(const float4*)&b1[(2 * w) * 16 + 4 * q];
        float4 bb1 = *(const float4*)&b1[(2 * w + 1) * 16 + 4 * q];
        fH0 = (f4v){bb0.x, bb0.y, bb0.z, bb0.w};
        fH1 = (f4v){bb1.x, bb1.y, bb1.z, bb1.w};
        f4v z = {0.f, 0.f, 0.f, 0.f};
        fL0 = z; fL1 = z;
    }
    #pragma unroll
    for (int kb = 0; kb < 8; ++kb) {
        hfrag ah = *reinterpret_cast<const hfrag*>(&LF[SW(kb * 256 + lane * 4)]);
        int fid0 = (kb * 16 + 2 * w) * 64 + lane;
        int fid1 = fid0 + 64;
        hfrag w0h = *reinterpret_cast<const hfrag*>(&wf1h[(size_t)fid0 * 4]);
        hfrag w1h = *reinterpret_cast<const hfrag*>(&wf1h[(size_t)fid1 * 4]);
        hfrag w0l = *reinterpret_cast<const hfrag*>(&wf1l[(size_t)fid0 * 4]);
        hfrag w1l = *reinterpret_cast<const hfrag*>(&wf1l[(size_t)fid1 * 4]);
        fH0 = __builtin_amdgcn_mfma_f32_16x16x32_f16(w0h, ah, fH0, 0, 0, 0);
        fH1 = __builtin_amdgcn_mfma_f32_16x16x32_f16(w1h, ah, fH1, 0, 0, 0);
        fL0 = __builtin_amdgcn_mfma_f32_16x16x32_f16(w0l, ah, fL0, 0, 0, 0);
        fL1 = __builtin_amdgcn_mfma_f32_16x16x32_f16(w1l, ah, fL1, 0, 0, 0);
    }

    // y = relu(...) into yb (aliases SH; step buffers dead, LF untouched)
    #pragma unroll
    for (int i = 0; i < 2; ++i) {
        int n0 = (2 * w + i) * 16 + 4 * q;
        f4v s = (i == 0) ? fH0 : fH1;
        f4v sl = (i == 0) ? fL0 : fL1;
        float4 yv;
        yv.x = fmaxf(s[0] + sl[0] * LO_DESCALE, 0.f);
        yv.y = fmaxf(s[1] + sl[1] * LO_DESCALE, 0.f);
        yv.z = fmaxf(s[2] + sl[2] * LO_DESCALE, 0.f);
        yv.w = fmaxf(s[3] + sl[3] * LO_DESCALE, 0.f);
        *reinterpret_cast<float4*>(&yb[col * 260 + n0]) = yv;
    }
    __syncthreads();

    // ---- FC2: 8 x 18 dots of length 256 ----
    if (tid < Mrows * Cv) {
        int r = tid & 7, cc = tid >> 3;
        float s = b2[cc];
        #pragma unroll 8
        for (int k4 = 0; k4 < Hv / 4; ++k4) {
            float4 yv = *reinterpret_cast<const float4*>(&yb[r * 260 + 4 * k4]);
            float4 wv2 = *(const float4*)&W2[cc * Hv + 4 * k4];
            s = fmaf(yv.x, wv2.x, s);
            s = fmaf(yv.y, wv2.y, s);
            s = fmaf(yv.z, wv2.z, s);
            s = fmaf(yv.w, wv2.w, s);
        }
        out[(rb + r) * Cv + cc] = s;
    }
}

extern "C" void kernel_launch(void* const* d_in, const int* in_sizes, int n_in,
                              void* d_out, int out_size, void* d_ws, size_t ws_size,
                              hipStream_t stream) {
    const int*   x_in  = (const int*)  d_in[0];
    const int*   x_len = (const int*)  d_in[1];
    const float* emb   = (const float*)d_in[2];
    const float* W_ih  = (const float*)d_in[3];
    const float* W_hh  = (const float*)d_in[4];
    const float* b_ih  = (const float*)d_in[5];
    const float* b_hh  = (const float*)d_in[6];
    const float* W1    = (const float*)d_in[7];
    const float* b1    = (const float*)d_in[8];
    const float* W2    = (const float*)d_in[9];
    const float* b2    = (const float*)d_in[10];
    float* out = (float*)d_out;

    unsigned* wfh  = (unsigned*)d_ws;         // 12288 frags * 16 B
    unsigned* wf1h = wfh  + 12288 * 4;        // 8192 * 16 B
    unsigned* wf1l = wf1h + 8192 * 4;         // 8192 * 16 B

    build_frags<<<80, 256, 0, stream>>>(W_ih, W_hh, W1, wfh, wf1h, wf1l);
    rnn_fused<<<Bv / Mrows, 512, 0, stream>>>(x_in, x_len, emb, wfh,
                                              wf1h, wf1l, b_ih, b_hh,
                                              b1, W2, b2, out);
}